// Round 2
// baseline (265.052 us; speedup 1.0000x reference)
//
#include <hip/hip_runtime.h>
#include <hip/hip_bf16.h>
#include <stdint.h>

#define D 128
#define TOPK 5
#define K1 6
#define CAP 128
#define TAU 0.30f
#define DUP 0.9999f
#define NSPLIT 48

typedef __bf16 bf16x8 __attribute__((ext_vector_type(8)));
typedef float f32x16 __attribute__((ext_vector_type(16)));
typedef unsigned int u32;

static __device__ __forceinline__ ushort f2bf(float x) {
    uint32_t u = __builtin_bit_cast(uint32_t, x);
    uint32_t r = (u + 0x7FFFu + ((u >> 16) & 1u)) >> 16;
    return (ushort)r;
}

// async global->LDS, 16B per lane. lds base is wave-uniform; HW adds lane*16.
static __device__ __forceinline__ void gl_lds16(const ushort* g, ushort* l) {
    __builtin_amdgcn_global_load_lds(
        (const __attribute__((address_space(1))) u32*)g,
        (__attribute__((address_space(3))) u32*)l, 16, 0, 0);
}

// ---- normalize users -> bf16 table in MFMA-tiled layout + inverse norms ----
// One 32-row group (8 KB tile) per block; tile built in LDS (scattered 4B
// stores, cheap), then written to global fully coalesced (16B/lane linear).
// Tiled layout within group: ushort off = (col>>3)*256 + r32*8 + (col&7).
__global__ __launch_bounds__(256) void k_norm_users(const float* __restrict__ u,
        ushort* __restrict__ ub, float* __restrict__ uinv, int nu) {
    __shared__ __align__(16) ushort tile[4096];
    const int g = blockIdx.x;
    const int wv = threadIdx.x >> 6, lane = threadIdx.x & 63;
    #pragma unroll
    for (int rr = 0; rr < 8; rr++) {
        int r32 = wv * 8 + rr;
        int row = g * 32 + r32;
        // this lane handles cols 2*lane, 2*lane+1 (same 8-col block)
        size_t loff = (size_t)(lane >> 2) * 256 + r32 * 8 + ((lane << 1) & 7);
        if (row < nu) {
            float2 v = ((const float2*)(u + (size_t)row * D))[lane];
            float s = v.x * v.x + v.y * v.y;
            #pragma unroll
            for (int o = 32; o; o >>= 1) s += __shfl_xor(s, o);
            float inv = 1.0f / fmaxf(sqrtf(s), 1e-12f);
            ushort2 w; w.x = f2bf(v.x * inv); w.y = f2bf(v.y * inv);
            *(ushort2*)(tile + loff) = w;
            if (lane == 0) uinv[row] = inv;
        } else {
            ushort2 z; z.x = 0; z.y = 0;
            *(ushort2*)(tile + loff) = z;
            if (lane == 0) uinv[row] = 0.f;
        }
    }
    __syncthreads();
    // coalesced 8KB linear write: 512 x 16B chunks, 2 passes of 256 threads
    const uint4* src = (const uint4*)tile;
    uint4* dst = (uint4*)(ub + (size_t)g * 4096);
    dst[threadIdx.x] = src[threadIdx.x];
    dst[threadIdx.x + 256] = src[threadIdx.x + 256];
}

// ---- normalize queries -> bf16 (row-major) + fp32 ----
__global__ __launch_bounds__(256) void k_norm_queries(const float* __restrict__ q,
        ushort* __restrict__ qb, float* __restrict__ qn, int nq) {
    int row = blockIdx.x * 4 + (threadIdx.x >> 6);
    int lane = threadIdx.x & 63;
    if (row >= nq) return;
    float2 v = ((const float2*)(q + (size_t)row * D))[lane];
    float s = v.x * v.x + v.y * v.y;
    #pragma unroll
    for (int o = 32; o; o >>= 1) s += __shfl_xor(s, o);
    float inv = 1.0f / fmaxf(sqrtf(s), 1e-12f);
    float2 w; w.x = v.x * inv; w.y = v.y * inv;
    ((float2*)(qn + (size_t)row * D))[lane] = w;
    ushort2 b; b.x = f2bf(w.x); b.y = f2bf(w.y);
    ((ushort2*)(qb + (size_t)row * D))[lane] = b;
}

// ---- bf16 MFMA GEMM + threshold filter ----
// Block = 4 waves sharing one A-tile stream (double-buffered LDS, async
// global_load_lds prefetch); each wave owns 64 resident queries -> block
// covers 256 queries. Grid = (nq/256) qtiles * NSPLIT usplits = 768 blocks
// = exactly 3/CU resident. A-traffic = 16 x 25.6MB (4x less than before).
// m97 one-barrier loop: stage(next) -> ds_read(cur) -> MFMA -> barrier.
__global__ __launch_bounds__(256, 3) void k_gemm_filter(
        const ushort* __restrict__ ub, const ushort* __restrict__ qb,
        int* __restrict__ cnt, int* __restrict__ cand,
        int ngroup, int nu) {
    __shared__ __align__(16) ushort smem[2][4096];
    const int tid = threadIdx.x;
    const int wv = tid >> 6, lane = tid & 63;
    const int half = lane >> 5, l31 = lane & 31;
    const int us = blockIdx.x % NSPLIT;   // bid%8 class == us%8 -> XCD-stable
    const int qt = blockIdx.x / NSPLIT;
    const int qbase = qt * 256 + wv * 64;

    // B-frags (queries), resident. B[k][n]: n=lane&31, k=8*half+j.
    bf16x8 bq0[8], bq1[8];
    {
        const ushort* q0 = qb + (size_t)(qbase + l31) * D + half * 8;
        #pragma unroll
        for (int kt = 0; kt < 8; kt++) {
            bq0[kt] = *(const bf16x8*)(q0 + kt * 16);
            bq1[kt] = *(const bf16x8*)(q0 + 32 * D + kt * 16);
        }
    }

    // prologue: stage first group into buf 0
    {
        const ushort* gs = ub + (size_t)us * 4096 + wv * 1024 + lane * 8;
        ushort* lb = &smem[0][wv * 1024];
        gl_lds16(gs, lb);
        gl_lds16(gs + 512, lb + 512);
    }
    __syncthreads();

    const int lds_off = half * 256 + l31 * 8;   // ushort offset of frag base
    int cur = 0;
    for (int g = us; g < ngroup; g += NSPLIT) {
        // issue next-group stage into the other buffer (prefetch)
        int gn = g + NSPLIT;
        if (gn < ngroup) {
            const ushort* gs = ub + (size_t)gn * 4096 + wv * 1024 + lane * 8;
            ushort* lb = &smem[cur ^ 1][wv * 1024];
            gl_lds16(gs, lb);
            gl_lds16(gs + 512, lb + 512);
        }

        // A-frags from current LDS buffer (8 x ds_read_b128, conflict-free)
        const ushort* lp = &smem[cur][lds_off];
        bf16x8 a[8];
        #pragma unroll
        for (int kt = 0; kt < 8; kt++) a[kt] = *(const bf16x8*)(lp + kt * 512);

        f32x16 acc0, acc1;
        #pragma unroll
        for (int i = 0; i < 16; i++) { acc0[i] = 0.f; acc1[i] = 0.f; }
        #pragma unroll
        for (int kt = 0; kt < 8; kt++) {
            acc0 = __builtin_amdgcn_mfma_f32_32x32x16_bf16(a[kt], bq0[kt], acc0, 0, 0, 0);
            acc1 = __builtin_amdgcn_mfma_f32_32x32x16_bf16(a[kt], bq1[kt], acc1, 0, 0, 0);
        }

        // cheap max-filter (log-depth tree); detailed scan only on a hit
        float m0 = fmaxf(fmaxf(fmaxf(acc0[0], acc0[1]), fmaxf(acc0[2], acc0[3])),
                         fmaxf(fmaxf(acc0[4], acc0[5]), fmaxf(acc0[6], acc0[7])));
        m0 = fmaxf(m0, fmaxf(fmaxf(fmaxf(acc0[8], acc0[9]), fmaxf(acc0[10], acc0[11])),
                             fmaxf(fmaxf(acc0[12], acc0[13]), fmaxf(acc0[14], acc0[15]))));
        float m1 = fmaxf(fmaxf(fmaxf(acc1[0], acc1[1]), fmaxf(acc1[2], acc1[3])),
                         fmaxf(fmaxf(acc1[4], acc1[5]), fmaxf(acc1[6], acc1[7])));
        m1 = fmaxf(m1, fmaxf(fmaxf(fmaxf(acc1[8], acc1[9]), fmaxf(acc1[10], acc1[11])),
                             fmaxf(fmaxf(acc1[12], acc1[13]), fmaxf(acc1[14], acc1[15]))));

        int ub0 = g * 32 + half * 4;
        if (m0 > TAU) {
            #pragma unroll
            for (int rg = 0; rg < 16; rg++) {
                float s0 = acc0[rg];
                if (s0 > TAU) {
                    int urow = ub0 + (rg & 3) + 8 * (rg >> 2);
                    if (urow < nu) {
                        int qq = qbase + l31;
                        int pos = atomicAdd(&cnt[qq], 1);
                        if (pos < CAP) cand[qq * CAP + pos] = urow;
                    }
                }
            }
        }
        if (m1 > TAU) {
            #pragma unroll
            for (int rg = 0; rg < 16; rg++) {
                float s1 = acc1[rg];
                if (s1 > TAU) {
                    int urow = ub0 + (rg & 3) + 8 * (rg >> 2);
                    if (urow < nu) {
                        int qq = qbase + 32 + l31;
                        int pos = atomicAdd(&cnt[qq], 1);
                        if (pos < CAP) cand[qq * CAP + pos] = urow;
                    }
                }
            }
        }

        __syncthreads();   // drains prefetch (vmcnt) + frees cur for overwrite
        cur ^= 1;
    }
}

// ---- exact fp32 rescore + top-6 + dup-mask + output ----
__global__ __launch_bounds__(256) void k_rescore(
        const float* __restrict__ users, const float* __restrict__ qn,
        const float* __restrict__ uinv,
        const int* __restrict__ cnt, const int* __restrict__ cand,
        float* __restrict__ out_emb, float* __restrict__ out_sc) {
    __shared__ float s_sc[CAP];
    __shared__ int s_id[CAP];
    __shared__ float s_outv[TOPK];
    __shared__ int s_outi[TOPK];
    int q = blockIdx.x;
    int tid = threadIdx.x, wv = tid >> 6, lane = tid & 63;
    int c = cnt[q]; c = c < CAP ? c : CAP;
    for (int j = tid; j < CAP; j += 256) { s_sc[j] = -1e30f; s_id[j] = 0; }
    __syncthreads();
    float2 qv = ((const float2*)(qn + (size_t)q * D))[lane];
    for (int j = wv; j < c; j += 4) {
        int u = cand[q * CAP + j];
        float2 uv = ((const float2*)(users + (size_t)u * D))[lane];
        float qu = qv.x * uv.x + qv.y * uv.y;
        #pragma unroll
        for (int o = 32; o; o >>= 1) qu += __shfl_xor(qu, o);
        if (lane == 0) { s_sc[j] = qu * uinv[u]; s_id[j] = u; }
    }
    __syncthreads();

    if (wv == 0) {
        // register-cached top-6 (value desc, slot asc tiebreak)
        float c0 = s_sc[lane], c1 = s_sc[lane + 64];
        bool u0 = false, u1 = false;
        float topv[K1]; int tops[K1];
        for (int k = 0; k < K1; k++) {
            float v0 = u0 ? -1e30f : c0;
            float v1 = u1 ? -1e30f : c1;
            float v = fmaxf(v0, v1);
            int sl = (v1 > v0) ? lane + 64 : lane;
            #pragma unroll
            for (int o = 32; o; o >>= 1) {
                float ov = __shfl_xor(v, o);
                int os = __shfl_xor(sl, o);
                if (ov > v || (ov == v && os < sl)) { v = ov; sl = os; }
            }
            topv[k] = v; tops[k] = sl;
            u0 = u0 || (sl == lane);
            u1 = u1 || (sl == lane + 64);
        }
        // dup-mask semantics: drop >=0.9999, take first 5, pad with last
        // valid; if none valid, raw top-5.
        int vk[K1]; int nv = 0;
        #pragma unroll
        for (int k = 0; k < K1; k++) { if (topv[k] < DUP) { vk[nv] = k; nv++; } }
        if (lane < TOPK) {
            int j = lane; int k;
            if (nv > 0) { int p = (j < nv - 1) ? j : (nv - 1); k = vk[p]; }
            else k = j;
            s_outi[j] = tops[k];
            s_outv[j] = topv[k];
        }
    }
    __syncthreads();
    for (int j = wv; j < TOPK; j += 4) {
        int sl = s_outi[j];
        int u = s_id[sl];
        float rn = uinv[u];
        float2 uv = ((const float2*)(users + (size_t)u * D))[lane];
        float2 o; o.x = uv.x * rn; o.y = uv.y * rn;
        ((float2*)(out_emb + ((size_t)q * TOPK + j) * D))[lane] = o;
        if (lane == 0) out_sc[q * TOPK + j] = s_outv[j];
    }
}

extern "C" void kernel_launch(void* const* d_in, const int* in_sizes, int n_in,
                              void* d_out, int out_size, void* d_ws, size_t ws_size,
                              hipStream_t stream) {
    const float* q = (const float*)d_in[0];
    const float* u = (const float*)d_in[1];
    int nq = in_sizes[0] / D;          // 4096
    int nu = in_sizes[1] / D;          // 100000
    int nchunk = (nu + 127) / 128;     // 782
    int npad = nchunk * 128;           // 100096
    int ngroup = npad / 32;            // 3128

    char* ws = (char*)d_ws;
    ushort* ub = (ushort*)ws;                       size_t o1 = (size_t)npad * D * 2;
    ushort* qb = (ushort*)(ws + o1);                size_t o2 = o1 + (size_t)nq * D * 2;
    float*  qn = (float*)(ws + o2);                 size_t o3 = o2 + (size_t)nq * D * 4;
    float*  uinv = (float*)(ws + o3);               size_t o4 = o3 + (size_t)npad * 4;
    int*    cnt = (int*)(ws + o4);                  size_t o5 = o4 + (size_t)nq * 4;
    int*    cand = (int*)(ws + o5);

    float* out_emb = (float*)d_out;
    float* out_sc = out_emb + (size_t)nq * TOPK * D;

    hipMemsetAsync(cnt, 0, (size_t)nq * 4, stream);
    k_norm_users<<<ngroup, 256, 0, stream>>>(u, ub, uinv, nu);
    k_norm_queries<<<(nq + 3) / 4, 256, 0, stream>>>(q, qb, qn, nq);
    k_gemm_filter<<<(nq / 256) * NSPLIT, 256, 0, stream>>>(ub, qb, cnt, cand, ngroup, nu);
    k_rescore<<<nq, 256, 0, stream>>>(u, qn, uinv, cnt, cand, out_emb, out_sc);
}

// Round 4
// 263.429 us; speedup vs baseline: 1.0062x; 1.0062x over previous
//
#include <hip/hip_runtime.h>
#include <hip/hip_bf16.h>
#include <stdint.h>

#define D 128
#define TOPK 5
#define K1 6
#define CAP 128
#define TAU 0.30f
#define DUP 0.9999f
#define NSPLIT 48

typedef __bf16 bf16x8 __attribute__((ext_vector_type(8)));
typedef float f32x16 __attribute__((ext_vector_type(16)));
typedef unsigned int u32;

static __device__ __forceinline__ ushort f2bf(float x) {
    uint32_t u = __builtin_bit_cast(uint32_t, x);
    uint32_t r = (u + 0x7FFFu + ((u >> 16) & 1u)) >> 16;
    return (ushort)r;
}

// async global->LDS, 16B per lane. lds base is wave-uniform; HW adds lane*16.
static __device__ __forceinline__ void gl_lds16(const ushort* g, ushort* l) {
    __builtin_amdgcn_global_load_lds(
        (const __attribute__((address_space(1))) u32*)g,
        (__attribute__((address_space(3))) u32*)l, 16, 0, 0);
}

// ---- normalize users -> bf16 table in MFMA-tiled layout + inverse norms ----
// One 32-row group (8 KB tile) per block; tile built in LDS, written out as
// fully-coalesced 16B/lane linear stores.
// Tiled layout within group: ushort off = (col>>3)*256 + r32*8 + (col&7).
__global__ __launch_bounds__(256) void k_norm_users(const float* __restrict__ u,
        ushort* __restrict__ ub, float* __restrict__ uinv, int nu) {
    __shared__ __align__(16) ushort tile[4096];
    const int g = blockIdx.x;
    const int wv = threadIdx.x >> 6, lane = threadIdx.x & 63;
    #pragma unroll
    for (int rr = 0; rr < 8; rr++) {
        int r32 = wv * 8 + rr;
        int row = g * 32 + r32;
        size_t loff = (size_t)(lane >> 2) * 256 + r32 * 8 + ((lane << 1) & 7);
        if (row < nu) {
            float2 v = ((const float2*)(u + (size_t)row * D))[lane];
            float s = v.x * v.x + v.y * v.y;
            #pragma unroll
            for (int o = 32; o; o >>= 1) s += __shfl_xor(s, o);
            float inv = 1.0f / fmaxf(sqrtf(s), 1e-12f);
            ushort2 w; w.x = f2bf(v.x * inv); w.y = f2bf(v.y * inv);
            *(ushort2*)(tile + loff) = w;
            if (lane == 0) uinv[row] = inv;
        } else {
            ushort2 z; z.x = 0; z.y = 0;
            *(ushort2*)(tile + loff) = z;
            if (lane == 0) uinv[row] = 0.f;
        }
    }
    __syncthreads();
    const uint4* src = (const uint4*)tile;
    uint4* dst = (uint4*)(ub + (size_t)g * 4096);
    dst[threadIdx.x] = src[threadIdx.x];
    dst[threadIdx.x + 256] = src[threadIdx.x + 256];
}

// ---- normalize queries -> bf16 (row-major) + fp32 ----
__global__ __launch_bounds__(256) void k_norm_queries(const float* __restrict__ q,
        ushort* __restrict__ qb, float* __restrict__ qn, int nq) {
    int row = blockIdx.x * 4 + (threadIdx.x >> 6);
    int lane = threadIdx.x & 63;
    if (row >= nq) return;
    float2 v = ((const float2*)(q + (size_t)row * D))[lane];
    float s = v.x * v.x + v.y * v.y;
    #pragma unroll
    for (int o = 32; o; o >>= 1) s += __shfl_xor(s, o);
    float inv = 1.0f / fmaxf(sqrtf(s), 1e-12f);
    float2 w; w.x = v.x * inv; w.y = v.y * inv;
    ((float2*)(qn + (size_t)row * D))[lane] = w;
    ushort2 b; b.x = f2bf(w.x); b.y = f2bf(w.y);
    ((ushort2*)(qb + (size_t)row * D))[lane] = b;
}

// ---- bf16 MFMA GEMM + threshold filter ----
// T3+T4 structure: 3-deep LDS buffer, prefetch distance 2, counted
// s_waitcnt vmcnt(4) + raw s_barrier (never drain to 0 in the loop).
// Per iter each wave issues 2 global_load_lds; vmcnt(4) = own oldest
// (current buffer's) loads retired; barrier makes that true block-wide.
// End barrier protects buffer reuse (stage@i overwrites slot read @i-1).
__global__ __launch_bounds__(256, 3) void k_gemm_filter(
        const ushort* __restrict__ ub, const ushort* __restrict__ qb,
        int* __restrict__ cnt, int* __restrict__ cand,
        int ngroup, int nu) {
    __shared__ __align__(16) ushort smem[3][4096];
    const int tid = threadIdx.x;
    const int wv = tid >> 6, lane = tid & 63;
    const int half = lane >> 5, l31 = lane & 31;
    const int us = blockIdx.x % NSPLIT;   // us%8 == bid%8 -> XCD-stable slice
    const int qt = blockIdx.x / NSPLIT;
    const int qbase = qt * 256 + wv * 64;

    // B-frags (queries), resident. B[k][n]: n=lane&31, k=8*half+j.
    bf16x8 bq0[8], bq1[8];
    {
        const ushort* q0 = qb + (size_t)(qbase + l31) * D + half * 8;
        #pragma unroll
        for (int kt = 0; kt < 8; kt++) {
            bq0[kt] = *(const bf16x8*)(q0 + kt * 16);
            bq1[kt] = *(const bf16x8*)(q0 + 32 * D + kt * 16);
        }
    }

    const int ntile = (ngroup - us + NSPLIT - 1) / NSPLIT;  // uniform in block
    const int glast = ngroup - 1;

    // stage tile ti into LDS buffer buf (2 x global_load_lds_dwordx4 / wave)
    #define STAGE(buf, ti) do {                                               \
        int g_ = us + (ti) * NSPLIT;                                          \
        g_ = g_ < ngroup ? g_ : glast; /* clamp: uniform count at tail */     \
        const ushort* gs_ = ub + (size_t)g_ * 4096 + wv * 1024 + lane * 8;    \
        ushort* lb_ = &smem[buf][wv * 1024];                                  \
        gl_lds16(gs_, lb_);                                                   \
        gl_lds16(gs_ + 512, lb_ + 512);                                       \
    } while (0)

    STAGE(0, 0);
    STAGE(1, 1);

    const int lds_off = half * 256 + l31 * 8;   // ushort offset of frag base
    int b0 = 0, b1 = 1, b2 = 2;                 // rotating buffer ids
    for (int i = 0; i < ntile; i++) {
        STAGE(b2, i + 2);                        // 2 more in flight (<=6)
        asm volatile("s_waitcnt vmcnt(4)" ::: "memory");  // buf[b0] complete
        __builtin_amdgcn_s_barrier();            // ... block-wide
        __builtin_amdgcn_sched_barrier(0);

        const ushort* lp = &smem[b0][lds_off];
        bf16x8 a[8];
        #pragma unroll
        for (int kt = 0; kt < 8; kt++) a[kt] = *(const bf16x8*)(lp + kt * 512);

        f32x16 acc0, acc1;
        #pragma unroll
        for (int i2 = 0; i2 < 16; i2++) { acc0[i2] = 0.f; acc1[i2] = 0.f; }
        #pragma unroll
        for (int kt = 0; kt < 8; kt++) {
            acc0 = __builtin_amdgcn_mfma_f32_32x32x16_bf16(a[kt], bq0[kt], acc0, 0, 0, 0);
            acc1 = __builtin_amdgcn_mfma_f32_32x32x16_bf16(a[kt], bq1[kt], acc1, 0, 0, 0);
        }

        // cheap max-filter; detailed scan only on a hit (rare)
        float m0 = fmaxf(fmaxf(fmaxf(acc0[0], acc0[1]), fmaxf(acc0[2], acc0[3])),
                         fmaxf(fmaxf(acc0[4], acc0[5]), fmaxf(acc0[6], acc0[7])));
        m0 = fmaxf(m0, fmaxf(fmaxf(fmaxf(acc0[8], acc0[9]), fmaxf(acc0[10], acc0[11])),
                             fmaxf(fmaxf(acc0[12], acc0[13]), fmaxf(acc0[14], acc0[15]))));
        float m1 = fmaxf(fmaxf(fmaxf(acc1[0], acc1[1]), fmaxf(acc1[2], acc1[3])),
                         fmaxf(fmaxf(acc1[4], acc1[5]), fmaxf(acc1[6], acc1[7])));
        m1 = fmaxf(m1, fmaxf(fmaxf(fmaxf(acc1[8], acc1[9]), fmaxf(acc1[10], acc1[11])),
                             fmaxf(fmaxf(acc1[12], acc1[13]), fmaxf(acc1[14], acc1[15]))));

        int g = us + i * NSPLIT;
        int ub0 = g * 32 + half * 4;
        if (m0 > TAU) {
            #pragma unroll
            for (int rg = 0; rg < 16; rg++) {
                float s0 = acc0[rg];
                if (s0 > TAU) {
                    int urow = ub0 + (rg & 3) + 8 * (rg >> 2);
                    if (urow < nu) {
                        int qq = qbase + l31;
                        int pos = atomicAdd(&cnt[qq], 1);
                        if (pos < CAP) cand[qq * CAP + pos] = urow;
                    }
                }
            }
        }
        if (m1 > TAU) {
            #pragma unroll
            for (int rg = 0; rg < 16; rg++) {
                float s1 = acc1[rg];
                if (s1 > TAU) {
                    int urow = ub0 + (rg & 3) + 8 * (rg >> 2);
                    if (urow < nu) {
                        int qq = qbase + 32 + l31;
                        int pos = atomicAdd(&cnt[qq], 1);
                        if (pos < CAP) cand[qq * CAP + pos] = urow;
                    }
                }
            }
        }

        __builtin_amdgcn_sched_barrier(0);
        __builtin_amdgcn_s_barrier();            // reads of buf[b0] done
        int t = b0; b0 = b1; b1 = b2; b2 = t;    // rotate
    }
    #undef STAGE
}

// ---- exact fp32 rescore + top-6 + dup-mask + output ----
__global__ __launch_bounds__(256) void k_rescore(
        const float* __restrict__ users, const float* __restrict__ qn,
        const float* __restrict__ uinv,
        const int* __restrict__ cnt, const int* __restrict__ cand,
        float* __restrict__ out_emb, float* __restrict__ out_sc) {
    __shared__ float s_sc[CAP];
    __shared__ int s_id[CAP];
    __shared__ float s_outv[TOPK];
    __shared__ int s_outi[TOPK];
    int q = blockIdx.x;
    int tid = threadIdx.x, wv = tid >> 6, lane = tid & 63;
    int c = cnt[q]; c = c < CAP ? c : CAP;
    for (int j = tid; j < CAP; j += 256) { s_sc[j] = -1e30f; s_id[j] = 0; }
    __syncthreads();
    float2 qv = ((const float2*)(qn + (size_t)q * D))[lane];
    for (int j = wv; j < c; j += 4) {
        int u = cand[q * CAP + j];
        float2 uv = ((const float2*)(users + (size_t)u * D))[lane];
        float qu = qv.x * uv.x + qv.y * uv.y;
        #pragma unroll
        for (int o = 32; o; o >>= 1) qu += __shfl_xor(qu, o);
        if (lane == 0) { s_sc[j] = qu * uinv[u]; s_id[j] = u; }
    }
    __syncthreads();

    if (wv == 0) {
        // register-cached top-6 (value desc, slot asc tiebreak)
        float c0 = s_sc[lane], c1 = s_sc[lane + 64];
        bool u0 = false, u1 = false;
        float topv[K1]; int tops[K1];
        for (int k = 0; k < K1; k++) {
            float v0 = u0 ? -1e30f : c0;
            float v1 = u1 ? -1e30f : c1;
            float v = fmaxf(v0, v1);
            int sl = (v1 > v0) ? lane + 64 : lane;
            #pragma unroll
            for (int o = 32; o; o >>= 1) {
                float ov = __shfl_xor(v, o);
                int os = __shfl_xor(sl, o);
                if (ov > v || (ov == v && os < sl)) { v = ov; sl = os; }
            }
            topv[k] = v; tops[k] = sl;
            u0 = u0 || (sl == lane);
            u1 = u1 || (sl == lane + 64);
        }
        // dup-mask: drop >=0.9999, take first 5, pad with last valid;
        // if none valid, raw top-5.
        int vk[K1]; int nv = 0;
        #pragma unroll
        for (int k = 0; k < K1; k++) { if (topv[k] < DUP) { vk[nv] = k; nv++; } }
        if (lane < TOPK) {
            int j = lane; int k;
            if (nv > 0) { int p = (j < nv - 1) ? j : (nv - 1); k = vk[p]; }
            else k = j;
            s_outi[j] = tops[k];
            s_outv[j] = topv[k];
        }
    }
    __syncthreads();
    for (int j = wv; j < TOPK; j += 4) {
        int sl = s_outi[j];
        int u = s_id[sl];
        float rn = uinv[u];
        float2 uv = ((const float2*)(users + (size_t)u * D))[lane];
        float2 o; o.x = uv.x * rn; o.y = uv.y * rn;
        ((float2*)(out_emb + ((size_t)q * TOPK + j) * D))[lane] = o;
        if (lane == 0) out_sc[q * TOPK + j] = s_outv[j];
    }
}

extern "C" void kernel_launch(void* const* d_in, const int* in_sizes, int n_in,
                              void* d_out, int out_size, void* d_ws, size_t ws_size,
                              hipStream_t stream) {
    const float* q = (const float*)d_in[0];
    const float* u = (const float*)d_in[1];
    int nq = in_sizes[0] / D;          // 4096
    int nu = in_sizes[1] / D;          // 100000
    int nchunk = (nu + 127) / 128;     // 782
    int npad = nchunk * 128;           // 100096
    int ngroup = npad / 32;            // 3128

    char* ws = (char*)d_ws;
    ushort* ub = (ushort*)ws;                       size_t o1 = (size_t)npad * D * 2;
    ushort* qb = (ushort*)(ws + o1);                size_t o2 = o1 + (size_t)nq * D * 2;
    float*  qn = (float*)(ws + o2);                 size_t o3 = o2 + (size_t)nq * D * 4;
    float*  uinv = (float*)(ws + o3);               size_t o4 = o3 + (size_t)npad * 4;
    int*    cnt = (int*)(ws + o4);                  size_t o5 = o4 + (size_t)nq * 4;
    int*    cand = (int*)(ws + o5);

    float* out_emb = (float*)d_out;
    float* out_sc = out_emb + (size_t)nq * TOPK * D;

    hipMemsetAsync(cnt, 0, (size_t)nq * 4, stream);
    k_norm_users<<<ngroup, 256, 0, stream>>>(u, ub, uinv, nu);
    k_norm_queries<<<(nq + 3) / 4, 256, 0, stream>>>(q, qb, qn, nq);
    k_gemm_filter<<<(nq / 256) * NSPLIT, 256, 0, stream>>>(ub, qb, cnt, cand, ngroup, nu);
    k_rescore<<<nq, 256, 0, stream>>>(u, qn, uinv, cnt, cand, out_emb, out_sc);
}